// Round 21
// baseline (407.630 us; speedup 1.0000x reference)
//
#include <hip/hip_runtime.h>

#define B_   64
#define C_   256
#define D_   128
#define HW_  1024
#define K_   1024
#define N_   65536
#define MARGIN_PREF 1.2e-3f

typedef __attribute__((ext_vector_type(8))) short short8;
typedef __attribute__((ext_vector_type(4))) float f32x4;

__device__ __forceinline__ unsigned short f2bf(float f) {   // RNE f32->bf16
    unsigned u = __float_as_uint(f);
    return (unsigned short)((u + 0x7FFFu + ((u >> 16) & 1u)) >> 16);
}
__device__ __forceinline__ unsigned long long packdk(float d, int k) {  // order-preserving
    unsigned u = __float_as_uint(d);
    u = (u & 0x80000000u) ? ~u : (u | 0x80000000u);
    return ((unsigned long long)u << 10) | (unsigned)k;
}
__device__ __forceinline__ unsigned long long min64(unsigned long long a, unsigned long long b) {
    return a < b ? a : b;
}

// numpy pairwise-sum emulation, n=128 — scalar 8-accumulator tree (verified R4-R20)
template <typename F>
__device__ __forceinline__ float np_sum128(F ld) {
#pragma clang fp contract(off)
    float r0 = ld(0), r1 = ld(1), r2 = ld(2), r3 = ld(3);
    float r4 = ld(4), r5 = ld(5), r6 = ld(6), r7 = ld(7);
#pragma unroll
    for (int i = 8; i < 128; i += 8) {
        r0 = r0 + ld(i + 0); r1 = r1 + ld(i + 1);
        r2 = r2 + ld(i + 2); r3 = r3 + ld(i + 3);
        r4 = r4 + ld(i + 4); r5 = r5 + ld(i + 5);
        r6 = r6 + ld(i + 6); r7 = r7 + ld(i + 7);
    }
    return ((r0 + r1) + (r2 + r3)) + ((r4 + r5) + (r6 + r7));
}

// ---------------- K0: enorm (np bins) + embed -> bf16, PRE-SWIZZLED rows ----------------
__global__ __launch_bounds__(256) void k0_norms(const float* __restrict__ embed,
                                                float* __restrict__ enorm,
                                                unsigned short* __restrict__ ebf) {
#pragma clang fp contract(off)
    int k = blockIdx.x * 256 + threadIdx.x;
    if (k >= K_) return;
    const float* e = embed + (size_t)k * D_;
    enorm[k] = np_sum128([&](int i) { float v = e[i]; return v * v; });
    const int sw = (k & 7) << 4;
    char* rowp = (char*)ebf + ((size_t)k << 8);
#pragma unroll
    for (int j = 0; j < 16; ++j) {            // 16B chunks, swizzle preserves chunks
        short8 v;
#pragma unroll
        for (int q = 0; q < 8; ++q) v[q] = (short)f2bf(e[j * 8 + q]);
        *(short8*)(rowp + ((j * 16) ^ sw)) = v;
    }
}

// ---------------- K1: einsum-f32 emulation (sequential c, mul+add, no FMA) + bf16 copy ----------------
__global__ __launch_bounds__(256) void k1_proj(const float* __restrict__ z,
                                               const float* __restrict__ w,
                                               const float* __restrict__ bias,
                                               float* __restrict__ zp,
                                               unsigned short* __restrict__ zbf) {
#pragma clang fp contract(off)
    __shared__ float zs[64][64];
    __shared__ float wsh[64][128];
    const int b   = blockIdx.x >> 4;
    const int hw0 = (blockIdx.x & 15) << 6;
    const int t   = threadIdx.x;
    const int hwg = (t & 7) * 8;
    const int dg  = (t >> 3) * 4;

    float acc[8][4];
#pragma unroll
    for (int i = 0; i < 8; ++i)
#pragma unroll
        for (int j = 0; j < 4; ++j) acc[i][j] = 0.f;

    for (int ct = 0; ct < C_; ct += 64) {
        __syncthreads();
#pragma unroll
        for (int i = 0; i < 16; ++i) {
            int idx = i * 256 + t;
            int cc = idx >> 6, hwl = idx & 63;
            zs[cc][hwl] = z[(((size_t)b * C_ + ct + cc) << 10) + hw0 + hwl];
        }
#pragma unroll
        for (int i = 0; i < 32; ++i) {
            int idx = i * 256 + t;
            int cc = idx >> 7, d = idx & 127;
            wsh[cc][d] = w[(size_t)d * C_ + ct + cc];
        }
        __syncthreads();
#pragma unroll 2
        for (int cc = 0; cc < 64; ++cc) {
            float4 za = *(const float4*)&zs[cc][hwg];
            float4 zb = *(const float4*)&zs[cc][hwg + 4];
            float4 wv = *(const float4*)&wsh[cc][dg];
            float zv[8]  = {za.x, za.y, za.z, za.w, zb.x, zb.y, zb.z, zb.w};
            float wva[4] = {wv.x, wv.y, wv.z, wv.w};
#pragma unroll
            for (int i = 0; i < 8; ++i)
#pragma unroll
                for (int j = 0; j < 4; ++j) {
                    float p = zv[i] * wva[j];
                    acc[i][j] = acc[i][j] + p;
                }
        }
    }
#pragma unroll
    for (int i = 0; i < 8; ++i)
#pragma unroll
        for (int j = 0; j < 4; ++j) {
            float v = acc[i][j] + bias[dg + j];
            size_t off = (((size_t)b * HW_ + hw0 + hwg + i) << 7) + dg + j;
            zp[off]  = v;
            zbf[off] = f2bf(v);
        }
}

// ---------------- K0z: znorm[n] = np.sum(zf*zf) per row (np bins) ----------------
__global__ __launch_bounds__(256) void k0z_znorm(const float* __restrict__ zp,
                                                 float* __restrict__ znorm) {
#pragma clang fp contract(off)
    __shared__ float zl[64][129];          // +1 pad: conflict-free column reads
    const int t = threadIdx.x, n0 = blockIdx.x * 64;
#pragma unroll
    for (int i = 0; i < 32; ++i) {
        int idx = i * 256 + t;
        zl[idx >> 7][idx & 127] = zp[(size_t)n0 * 128 + idx];
    }
    __syncthreads();
    if (t < 64)
        znorm[n0 + t] = np_sum128([&](int i) { float v = zl[t][i]; return v * v; });
}

// ---------------- K2: barrier-free wave-private pipeline + exact np-bin rescue ----------------
// R17/R20's proven pass bodies; the per-iteration __syncthreads (vmcnt(0) drain in
// lockstep, the measured ~2100cyc/period floor) is REPLACED by wave-private LDS
// double-buffering with counted `s_waitcnt vmcnt(4)` (never 0 in-loop, T4 pattern).
// Only ONE block barrier (enorm LDS staging). 16-k tiles, depth-2 prefetch.
__global__ __launch_bounds__(256) void k2_argmin(const unsigned short* __restrict__ zbf,
                                                 const unsigned short* __restrict__ ebf,
                                                 const float* __restrict__ zp,
                                                 const float* __restrict__ embed,
                                                 const float* __restrict__ enorm,
                                                 const float* __restrict__ znorm,
                                                 int* __restrict__ bestk_ws,
                                                 float* __restrict__ out_idx) {
    __shared__ unsigned char wbuf[4][2][4096];     // per-wave double buffer (16 k x 256B)
    __shared__ float els[1024];                    // enorm, block-resident
    const int t   = threadIdx.x;
    const int l   = t & 63;
    const int wid = t >> 6;                        // 0..3
    const int r0  = (blockIdx.x * 4 + wid) * 16;   // wave's 16 rows
    const int lr  = l & 15;
    const int lh  = l >> 4;

    // z fragments (B operand): 4 d-tiles (mapping verified R9-R20)
    short8 zfrag[4];
#pragma unroll
    for (int dt = 0; dt < 4; ++dt) {
        zfrag[dt] = *(const short8*)(zbf + (((size_t)(r0 + lr)) << 7) + dt * 32 + lh * 8);
        asm volatile("" : "+v"(zfrag[dt]));
    }

    // per-lane swizzled ds_read offsets (row lr, logical col dt*64+lh*16)
    const int swz = (lr & 7) << 4;
    int roff[4];
#pragma unroll
    for (int dt = 0; dt < 4; ++dt)
        roff[dt] = lr * 256 + ((dt * 64 + lh * 16) ^ swz);

    // stage enorm to LDS (coalesced, once)
#pragma unroll
    for (int i = 0; i < 4; ++i) els[i * 256 + t] = enorm[i * 256 + t];
    __syncthreads();                               // only block barrier; zeroes vmcnt too

    const char* ebf_b = (const char*)ebf;
    auto STAGE = [&](int tile, int b) {            // wave-private async 4KB tile -> LDS
#pragma unroll
        for (int j = 0; j < 4; ++j) {
            __builtin_amdgcn_global_load_lds(
                (const __attribute__((address_space(1))) void*)(ebf_b + ((size_t)tile << 12) + j * 1024 + (l << 4)),
                (__attribute__((address_space(3))) void*)(&wbuf[wid][b][j * 1024 + (l << 4)]),
                16, 0, 0);
        }
    };

    // ---- Pass A: f32 running MIN of dist only (branch-free) ----
    float bmin = 1e30f;
    auto computeA = [&](int tile, const unsigned char* buf) {
        short8 af[4];
#pragma unroll
        for (int dt = 0; dt < 4; ++dt)
            af[dt] = *(const short8*)(buf + roff[dt]);
        f32x4 en4 = *(const f32x4*)(els + tile * 16 + lh * 4);
        f32x4 acc = {0.f, 0.f, 0.f, 0.f};
#pragma unroll
        for (int dt = 0; dt < 4; ++dt)
            acc = __builtin_amdgcn_mfma_f32_16x16x32_bf16(af[dt], zfrag[dt], acc, 0, 0, 0);
#pragma unroll
        for (int reg = 0; reg < 4; ++reg)
            bmin = fminf(bmin, fmaf(-2.f, acc[reg], en4[reg]));
    };

    STAGE(0, 0); STAGE(1, 1);
#pragma unroll 1
    for (int tt = 0; tt < 63; ++tt) {
        asm volatile("s_waitcnt vmcnt(4)" ::: "memory");   // tile tt landed; tt+1 in flight
        __builtin_amdgcn_sched_barrier(0);
        computeA(tt, wbuf[wid][tt & 1]);
        __builtin_amdgcn_sched_barrier(0);
        if (tt < 62) STAGE(tt + 2, tt & 1);                // af already in regs (lgkm dep)
    }
    asm volatile("s_waitcnt vmcnt(0)" ::: "memory");
    __builtin_amdgcn_sched_barrier(0);
    computeA(63, wbuf[wid][1]);

    {   // row-min across lanes {lr, lr+16, lr+32, lr+48}
        bmin = fminf(bmin, __shfl_xor(bmin, 16, 64));
        bmin = fminf(bmin, __shfl_xor(bmin, 32, 64));
    }
    const float thr = bmin + MARGIN_PREF;

    // ---- Pass B: bitwise-identical recompute, collect candidates ----
    unsigned long long ca = 0, cb = 0;             // 12 x 10-bit candidate slots
    int cnt = 0;
    auto computeB = [&](int tile, const unsigned char* buf) {
        short8 af[4];
#pragma unroll
        for (int dt = 0; dt < 4; ++dt)
            af[dt] = *(const short8*)(buf + roff[dt]);
        f32x4 en4 = *(const f32x4*)(els + tile * 16 + lh * 4);
        f32x4 acc = {0.f, 0.f, 0.f, 0.f};
#pragma unroll
        for (int dt = 0; dt < 4; ++dt)
            acc = __builtin_amdgcn_mfma_f32_16x16x32_bf16(af[dt], zfrag[dt], acc, 0, 0, 0);
#pragma unroll
        for (int reg = 0; reg < 4; ++reg) {
            float dist = fmaf(-2.f, acc[reg], en4[reg]);
            if (dist < thr) {                      // window vs TRUE row min
                int kk = tile * 16 + lh * 4 + reg;
                if (cnt < 6)       ca |= (unsigned long long)kk << (10 * cnt);
                else if (cnt < 12) cb |= (unsigned long long)kk << (10 * (cnt - 6));
                ++cnt;
            }
        }
    };

    STAGE(0, 0); STAGE(1, 1);
#pragma unroll 1
    for (int tt = 0; tt < 63; ++tt) {
        asm volatile("s_waitcnt vmcnt(4)" ::: "memory");
        __builtin_amdgcn_sched_barrier(0);
        computeB(tt, wbuf[wid][tt & 1]);
        __builtin_amdgcn_sched_barrier(0);
        if (tt < 62) STAGE(tt + 2, tt & 1);
    }
    asm volatile("s_waitcnt vmcnt(0)" ::: "memory");
    __builtin_amdgcn_sched_barrier(0);
    computeB(63, wbuf[wid][1]);

    // ---- Phase C: exact np-bin refine of candidates (R4-verified chain) ----
    const int myrow = r0 + lr;
    const float* zrow = zp + ((size_t)myrow << 7);
    const float  zn   = znorm[myrow];
    unsigned long long best = ~0ull;

    auto refine = [&](int kk) {
#pragma clang fp contract(off)
        const float* e = embed + ((size_t)kk << 7);
        float s = 0.f;
#pragma unroll 1
        for (int d = 0; d < 128; ++d) s = fmaf(zrow[d], e[d], s);
        float T  = 2.0f * s;
        float A  = zn - T;                  // bin-maker 1 (mag ~13)
        float Bv = A + enorm[kk];           // bin-maker 2
        best = min64(best, packdk(Bv, kk)); // lex (bin, k) = np first-occurrence
    };

    if (cnt <= 12) {
#pragma unroll
        for (int i = 0; i < 6; ++i)
            if (i < cnt) refine((int)((ca >> (10 * i)) & 1023ull));
#pragma unroll
        for (int i = 6; i < 12; ++i)
            if (i < cnt) refine((int)((cb >> (10 * (i - 6))) & 1023ull));
    } else {                                // overflow fallback: lane's whole 256-k subset
#pragma unroll 1
        for (int kt = 0; kt < 64; ++kt)
#pragma unroll
            for (int reg = 0; reg < 4; ++reg) refine(kt * 16 + lh * 4 + reg);
    }
    {   // row-min across lanes {lr, lr+16, lr+32, lr+48}
        unsigned long long o;
        o = __shfl_xor(best, 16, 64); best = min64(best, o);
        o = __shfl_xor(best, 32, 64); best = min64(best, o);
    }
    if (l < 16) {
        int kk = (int)(best & 1023ull);
        bestk_ws[r0 + l] = kk;
        out_idx[r0 + l]  = (float)kk;
    }
}

// ---------------- K3: gather + NCHW transpose ----------------
__global__ __launch_bounds__(256) void k3_gather(const float* __restrict__ embed,
                                                 const int* __restrict__ bestk,
                                                 float* __restrict__ out0) {
    __shared__ float tile[64][129];
    const int b   = blockIdx.x >> 4;
    const int hw0 = (blockIdx.x & 15) << 6;
    const int t   = threadIdx.x;
    const int n0  = b * HW_ + hw0;
#pragma unroll
    for (int i = 0; i < 32; ++i) {
        int idx = i * 256 + t;
        int hwl = idx >> 7, d = idx & 127;
        int k = bestk[n0 + hwl];
        tile[hwl][d] = embed[(size_t)k * 128 + d];
    }
    __syncthreads();
#pragma unroll
    for (int i = 0; i < 32; ++i) {
        int idx = i * 256 + t;
        int d = idx >> 6, hwl = idx & 63;
        out0[(((size_t)b * D_ + d) << 10) + hw0 + hwl] = tile[hwl][d];
    }
}

extern "C" void kernel_launch(void* const* d_in, const int* in_sizes, int n_in,
                              void* d_out, int out_size, void* d_ws, size_t ws_size,
                              hipStream_t stream) {
    const float* z     = (const float*)d_in[0];
    const float* pw    = (const float*)d_in[1];
    const float* pb    = (const float*)d_in[2];
    const float* embed = (const float*)d_in[3];

    float* out0 = (float*)d_out;
    float* out1 = (float*)d_out + (size_t)B_ * D_ * HW_;

    char* ws = (char*)d_ws;
    float*          zp    = (float*)ws;                                   // 32 MB
    unsigned short* zbf   = (unsigned short*)(ws + (32u << 20));          // 16 MB
    unsigned short* ebf   = (unsigned short*)(ws + (48u << 20));          // 256 KB
    float*          enorm = (float*)(ws + (48u << 20) + (256u << 10));    // 4 KB
    float*          znorm = (float*)(ws + (49u << 20));                   // 256 KB
    int*            bestk = (int*)  (ws + (50u << 20));                   // 256 KB

    hipLaunchKernelGGL(k0_norms,  dim3(4),    dim3(256), 0, stream, embed, enorm, ebf);
    hipLaunchKernelGGL(k1_proj,   dim3(1024), dim3(256), 0, stream, z, pw, pb, zp, zbf);
    hipLaunchKernelGGL(k0z_znorm, dim3(1024), dim3(256), 0, stream, zp, znorm);
    hipLaunchKernelGGL(k2_argmin, dim3(1024), dim3(256), 0, stream,
                       zbf, ebf, zp, embed, enorm, znorm, bestk, out1);
    hipLaunchKernelGGL(k3_gather, dim3(1024), dim3(256), 0, stream, embed, bestk, out0);
}

// Round 22
// 369.459 us; speedup vs baseline: 1.1033x; 1.1033x over previous
//
#include <hip/hip_runtime.h>

#define B_   64
#define C_   256
#define D_   128
#define HW_  1024
#define K_   1024
#define N_   65536
#define MARGIN_PREF 1.2e-3f

typedef __attribute__((ext_vector_type(8))) short short8;
typedef __attribute__((ext_vector_type(4))) float f32x4;

__device__ __forceinline__ unsigned short f2bf(float f) {   // RNE f32->bf16
    unsigned u = __float_as_uint(f);
    return (unsigned short)((u + 0x7FFFu + ((u >> 16) & 1u)) >> 16);
}
__device__ __forceinline__ unsigned long long packdk(float d, int k) {  // order-preserving
    unsigned u = __float_as_uint(d);
    u = (u & 0x80000000u) ? ~u : (u | 0x80000000u);
    return ((unsigned long long)u << 10) | (unsigned)k;
}
__device__ __forceinline__ float unpackd(unsigned long long key) {
    unsigned u = (unsigned)(key >> 10);
    u = (u & 0x80000000u) ? (u ^ 0x80000000u) : ~u;
    return __uint_as_float(u);
}
__device__ __forceinline__ unsigned long long min64(unsigned long long a, unsigned long long b) {
    return a < b ? a : b;
}

// numpy pairwise-sum emulation, n=128 — scalar 8-accumulator tree (verified R4-R21)
template <typename F>
__device__ __forceinline__ float np_sum128(F ld) {
#pragma clang fp contract(off)
    float r0 = ld(0), r1 = ld(1), r2 = ld(2), r3 = ld(3);
    float r4 = ld(4), r5 = ld(5), r6 = ld(6), r7 = ld(7);
#pragma unroll
    for (int i = 8; i < 128; i += 8) {
        r0 = r0 + ld(i + 0); r1 = r1 + ld(i + 1);
        r2 = r2 + ld(i + 2); r3 = r3 + ld(i + 3);
        r4 = r4 + ld(i + 4); r5 = r5 + ld(i + 5);
        r6 = r6 + ld(i + 6); r7 = r7 + ld(i + 7);
    }
    return ((r0 + r1) + (r2 + r3)) + ((r4 + r5) + (r6 + r7));
}

// ---------------- K0: enorm (np bins) + embed -> bf16, PRE-SWIZZLED rows ----------------
__global__ __launch_bounds__(256) void k0_norms(const float* __restrict__ embed,
                                                float* __restrict__ enorm,
                                                unsigned short* __restrict__ ebf) {
#pragma clang fp contract(off)
    int k = blockIdx.x * 256 + threadIdx.x;
    if (k >= K_) return;
    const float* e = embed + (size_t)k * D_;
    enorm[k] = np_sum128([&](int i) { float v = e[i]; return v * v; });
    const int sw = (k & 7) << 4;
    char* rowp = (char*)ebf + ((size_t)k << 8);
#pragma unroll
    for (int j = 0; j < 16; ++j) {            // 16B chunks, swizzle preserves chunks
        short8 v;
#pragma unroll
        for (int q = 0; q < 8; ++q) v[q] = (short)f2bf(e[j * 8 + q]);
        *(short8*)(rowp + ((j * 16) ^ sw)) = v;
    }
}

// ---------------- K1: einsum-f32 emulation (sequential c, mul+add, no FMA) + bf16 copy ----------------
__global__ __launch_bounds__(256) void k1_proj(const float* __restrict__ z,
                                               const float* __restrict__ w,
                                               const float* __restrict__ bias,
                                               float* __restrict__ zp,
                                               unsigned short* __restrict__ zbf) {
#pragma clang fp contract(off)
    __shared__ float zs[64][64];
    __shared__ float wsh[64][128];
    const int b   = blockIdx.x >> 4;
    const int hw0 = (blockIdx.x & 15) << 6;
    const int t   = threadIdx.x;
    const int hwg = (t & 7) * 8;
    const int dg  = (t >> 3) * 4;

    float acc[8][4];
#pragma unroll
    for (int i = 0; i < 8; ++i)
#pragma unroll
        for (int j = 0; j < 4; ++j) acc[i][j] = 0.f;

    for (int ct = 0; ct < C_; ct += 64) {
        __syncthreads();
#pragma unroll
        for (int i = 0; i < 16; ++i) {
            int idx = i * 256 + t;
            int cc = idx >> 6, hwl = idx & 63;
            zs[cc][hwl] = z[(((size_t)b * C_ + ct + cc) << 10) + hw0 + hwl];
        }
#pragma unroll
        for (int i = 0; i < 32; ++i) {
            int idx = i * 256 + t;
            int cc = idx >> 7, d = idx & 127;
            wsh[cc][d] = w[(size_t)d * C_ + ct + cc];
        }
        __syncthreads();
#pragma unroll 2
        for (int cc = 0; cc < 64; ++cc) {
            float4 za = *(const float4*)&zs[cc][hwg];
            float4 zb = *(const float4*)&zs[cc][hwg + 4];
            float4 wv = *(const float4*)&wsh[cc][dg];
            float zv[8]  = {za.x, za.y, za.z, za.w, zb.x, zb.y, zb.z, zb.w};
            float wva[4] = {wv.x, wv.y, wv.z, wv.w};
#pragma unroll
            for (int i = 0; i < 8; ++i)
#pragma unroll
                for (int j = 0; j < 4; ++j) {
                    float p = zv[i] * wva[j];
                    acc[i][j] = acc[i][j] + p;
                }
        }
    }
#pragma unroll
    for (int i = 0; i < 8; ++i)
#pragma unroll
        for (int j = 0; j < 4; ++j) {
            float v = acc[i][j] + bias[dg + j];
            size_t off = (((size_t)b * HW_ + hw0 + hwg + i) << 7) + dg + j;
            zp[off]  = v;
            zbf[off] = f2bf(v);
        }
}

// ---------------- K0z: znorm[n] = np.sum(zf*zf) per row (np bins) ----------------
__global__ __launch_bounds__(256) void k0z_znorm(const float* __restrict__ zp,
                                                 float* __restrict__ znorm) {
#pragma clang fp contract(off)
    __shared__ float zl[64][129];          // +1 pad: conflict-free column reads
    const int t = threadIdx.x, n0 = blockIdx.x * 64;
#pragma unroll
    for (int i = 0; i < 32; ++i) {
        int idx = i * 256 + t;
        zl[idx >> 7][idx & 127] = zp[(size_t)n0 * 128 + idx];
    }
    __syncthreads();
    if (t < 64)
        znorm[n0 + t] = np_sum128([&](int i) { float v = zl[t][i]; return v * v; });
}

// ---------------- K2: GEMM-shaped two-pass MFMA prefilter + exact np-bin rescue ----------------
// Arithmetic-intensity fix: block = 128 rows (4 waves x 2 row-frags), k-step 64.
// Each staged e-fragment read feeds 2 MFMAs (ratio 2.0 vs R17's 0.5); 16 iters/pass;
// 4x fewer LDS bytes/wave. Pass bodies keep R9/R17's regalloc-proven forms.
__global__ __launch_bounds__(256) void k2_argmin(const unsigned short* __restrict__ zbf,
                                                 const unsigned short* __restrict__ ebf,
                                                 const float* __restrict__ zp,
                                                 const float* __restrict__ embed,
                                                 const float* __restrict__ enorm,
                                                 const float* __restrict__ znorm,
                                                 int* __restrict__ bestk_ws,
                                                 float* __restrict__ out_idx) {
    __shared__ unsigned char etile[2][64 * 256];   // dbuf 16KB: 64 k-rows x 256B (pre-swizzled)
    __shared__ float els[1024];                    // enorm, block-resident
    const int t   = threadIdx.x;
    const int l   = t & 63;
    const int wid = t >> 6;                        // 0..3
    const int r0  = blockIdx.x * 128 + wid * 32;   // wave's 32 rows (2 row-frags)
    const int lr  = l & 15;
    const int lh  = l >> 4;

    // z fragments (B operand): 2 row-frags x 4 d-tiles (R9-proven shape)
    short8 zfrag[2][4];
#pragma unroll
    for (int rt = 0; rt < 2; ++rt)
#pragma unroll
        for (int dt = 0; dt < 4; ++dt)
            zfrag[rt][dt] = *(const short8*)(zbf + (((size_t)(r0 + rt * 16 + lr)) << 7) + dt * 32 + lh * 8);

    // per-lane swizzled ds_read offsets (e-row lr within 16-k frag, col dt*64+lh*16)
    const int swz = (lr & 7) << 4;
    int roff[4];
#pragma unroll
    for (int dt = 0; dt < 4; ++dt)
        roff[dt] = lr * 256 + ((dt * 64 + lh * 16) ^ swz);

    const char* ebf_b = (const char*)ebf;
    auto STAGE = [&](int st, int b) {              // async 16KB k-step tile -> LDS
#pragma unroll
        for (int j = 0; j < 4; ++j) {
            int off = j * 4096 + (t << 4);
            __builtin_amdgcn_global_load_lds(
                (const __attribute__((address_space(1))) void*)(ebf_b + ((size_t)st << 14) + off),
                (__attribute__((address_space(3))) void*)(&etile[b][off]),
                16, 0, 0);
        }
    };

    // stage enorm to LDS (coalesced, once)
#pragma unroll
    for (int i = 0; i < 4; ++i) els[i * 256 + t] = enorm[i * 256 + t];

    // ---- Pass A: f32 running MIN per row-frag (branch-free, no k-tracking) ----
    float bmin0 = 1e30f, bmin1 = 1e30f;
    STAGE(0, 0);
#pragma unroll 1
    for (int st = 0; st < 16; ++st) {
        __syncthreads();                           // drains stage(st) (+ els first time)
        if (st < 15) STAGE(st + 1, (st + 1) & 1);
        const unsigned char* buf = etile[st & 1];
#pragma unroll
        for (int kf = 0; kf < 4; ++kf) {
            short8 af[4];
#pragma unroll
            for (int dt = 0; dt < 4; ++dt)
                af[dt] = *(const short8*)(buf + kf * 4096 + roff[dt]);
            f32x4 en4 = *(const f32x4*)(els + st * 64 + kf * 16 + lh * 4);
            f32x4 a0 = {0.f, 0.f, 0.f, 0.f};
            f32x4 a1 = {0.f, 0.f, 0.f, 0.f};
#pragma unroll
            for (int dt = 0; dt < 4; ++dt)
                a0 = __builtin_amdgcn_mfma_f32_16x16x32_bf16(af[dt], zfrag[0][dt], a0, 0, 0, 0);
#pragma unroll
            for (int dt = 0; dt < 4; ++dt)
                a1 = __builtin_amdgcn_mfma_f32_16x16x32_bf16(af[dt], zfrag[1][dt], a1, 0, 0, 0);
#pragma unroll
            for (int reg = 0; reg < 4; ++reg) {
                bmin0 = fminf(bmin0, fmaf(-2.f, a0[reg], en4[reg]));
                bmin1 = fminf(bmin1, fmaf(-2.f, a1[reg], en4[reg]));
            }
        }
    }
    {   // row-min across lanes {lr, lr+16, lr+32, lr+48}
        bmin0 = fminf(bmin0, __shfl_xor(bmin0, 16, 64));
        bmin0 = fminf(bmin0, __shfl_xor(bmin0, 32, 64));
        bmin1 = fminf(bmin1, __shfl_xor(bmin1, 16, 64));
        bmin1 = fminf(bmin1, __shfl_xor(bmin1, 32, 64));
    }
    const float thr0 = bmin0 + MARGIN_PREF;
    const float thr1 = bmin1 + MARGIN_PREF;

    // ---- Pass B: bitwise-identical recompute, collect candidates (R9-proven form) ----
    unsigned long long ca0 = 0, cb0 = 0, ca1 = 0, cb1 = 0;
    int cnt0 = 0, cnt1 = 0;
    __syncthreads();
    STAGE(0, 0);
#pragma unroll 1
    for (int st = 0; st < 16; ++st) {
        __syncthreads();
        if (st < 15) STAGE(st + 1, (st + 1) & 1);
        const unsigned char* buf = etile[st & 1];
#pragma unroll
        for (int kf = 0; kf < 4; ++kf) {
            short8 af[4];
#pragma unroll
            for (int dt = 0; dt < 4; ++dt)
                af[dt] = *(const short8*)(buf + kf * 4096 + roff[dt]);
            f32x4 en4 = *(const f32x4*)(els + st * 64 + kf * 16 + lh * 4);
            f32x4 a0 = {0.f, 0.f, 0.f, 0.f};
            f32x4 a1 = {0.f, 0.f, 0.f, 0.f};
#pragma unroll
            for (int dt = 0; dt < 4; ++dt)
                a0 = __builtin_amdgcn_mfma_f32_16x16x32_bf16(af[dt], zfrag[0][dt], a0, 0, 0, 0);
#pragma unroll
            for (int dt = 0; dt < 4; ++dt)
                a1 = __builtin_amdgcn_mfma_f32_16x16x32_bf16(af[dt], zfrag[1][dt], a1, 0, 0, 0);
#pragma unroll
            for (int reg = 0; reg < 4; ++reg) {
                int kk = st * 64 + kf * 16 + lh * 4 + reg;
                float d0 = fmaf(-2.f, a0[reg], en4[reg]);
                if (d0 < thr0) {
                    if (cnt0 < 6)       ca0 |= (unsigned long long)kk << (10 * cnt0);
                    else if (cnt0 < 12) cb0 |= (unsigned long long)kk << (10 * (cnt0 - 6));
                    ++cnt0;
                }
                float d1 = fmaf(-2.f, a1[reg], en4[reg]);
                if (d1 < thr1) {
                    if (cnt1 < 6)       ca1 |= (unsigned long long)kk << (10 * cnt1);
                    else if (cnt1 < 12) cb1 |= (unsigned long long)kk << (10 * (cnt1 - 6));
                    ++cnt1;
                }
            }
        }
    }

    // ---- Phase C: exact np-bin refine of candidates (R4-verified chain) ----
    unsigned long long fin[2];
#pragma unroll
    for (int rt = 0; rt < 2; ++rt) {
        const int myrow = r0 + rt * 16 + lr;
        const float* zrow = zp + ((size_t)myrow << 7);
        const float  zn   = znorm[myrow];
        unsigned long long best = ~0ull;
        unsigned long long ca = rt == 0 ? ca0 : ca1, cb = rt == 0 ? cb0 : cb1;
        int cnt = rt == 0 ? cnt0 : cnt1;

        auto refine = [&](int kk) {
#pragma clang fp contract(off)
            const float* e = embed + ((size_t)kk << 7);
            float s = 0.f;
#pragma unroll 1
            for (int d = 0; d < 128; ++d) s = fmaf(zrow[d], e[d], s);
            float T  = 2.0f * s;
            float A  = zn - T;                  // bin-maker 1 (mag ~13)
            float Bv = A + enorm[kk];           // bin-maker 2
            best = min64(best, packdk(Bv, kk)); // lex (bin, k) = np first-occurrence
        };

        if (cnt <= 12) {
#pragma unroll
            for (int i = 0; i < 6; ++i)
                if (i < cnt) refine((int)((ca >> (10 * i)) & 1023ull));
#pragma unroll
            for (int i = 6; i < 12; ++i)
                if (i < cnt) refine((int)((cb >> (10 * (i - 6))) & 1023ull));
        } else {                                // overflow fallback: lane's k-subset
#pragma unroll 1
            for (int st = 0; st < 16; ++st)
#pragma unroll
                for (int kf = 0; kf < 4; ++kf)
#pragma unroll
                    for (int reg = 0; reg < 4; ++reg)
                        refine(st * 64 + kf * 16 + lh * 4 + reg);
        }
        unsigned long long o;
        o = __shfl_xor(best, 16, 64); best = min64(best, o);
        o = __shfl_xor(best, 32, 64); best = min64(best, o);
        fin[rt] = best;
    }

    if (l < 16) {
#pragma unroll
        for (int rt = 0; rt < 2; ++rt) {
            int row = r0 + rt * 16 + l;
            int kk  = (int)(fin[rt] & 1023ull);
            bestk_ws[row] = kk;
            out_idx[row]  = (float)kk;
        }
    }
}

// ---------------- K3: gather + NCHW transpose ----------------
__global__ __launch_bounds__(256) void k3_gather(const float* __restrict__ embed,
                                                 const int* __restrict__ bestk,
                                                 float* __restrict__ out0) {
    __shared__ float tile[64][129];
    const int b   = blockIdx.x >> 4;
    const int hw0 = (blockIdx.x & 15) << 6;
    const int t   = threadIdx.x;
    const int n0  = b * HW_ + hw0;
#pragma unroll
    for (int i = 0; i < 32; ++i) {
        int idx = i * 256 + t;
        int hwl = idx >> 7, d = idx & 127;
        int k = bestk[n0 + hwl];
        tile[hwl][d] = embed[(size_t)k * 128 + d];
    }
    __syncthreads();
#pragma unroll
    for (int i = 0; i < 32; ++i) {
        int idx = i * 256 + t;
        int d = idx >> 6, hwl = idx & 63;
        out0[(((size_t)b * D_ + d) << 10) + hw0 + hwl] = tile[hwl][d];
    }
}

extern "C" void kernel_launch(void* const* d_in, const int* in_sizes, int n_in,
                              void* d_out, int out_size, void* d_ws, size_t ws_size,
                              hipStream_t stream) {
    const float* z     = (const float*)d_in[0];
    const float* pw    = (const float*)d_in[1];
    const float* pb    = (const float*)d_in[2];
    const float* embed = (const float*)d_in[3];

    float* out0 = (float*)d_out;
    float* out1 = (float*)d_out + (size_t)B_ * D_ * HW_;

    char* ws = (char*)d_ws;
    float*          zp    = (float*)ws;                                   // 32 MB
    unsigned short* zbf   = (unsigned short*)(ws + (32u << 20));          // 16 MB
    unsigned short* ebf   = (unsigned short*)(ws + (48u << 20));          // 256 KB
    float*          enorm = (float*)(ws + (48u << 20) + (256u << 10));    // 4 KB
    float*          znorm = (float*)(ws + (49u << 20));                   // 256 KB
    int*            bestk = (int*)  (ws + (50u << 20));                   // 256 KB

    hipLaunchKernelGGL(k0_norms,  dim3(4),    dim3(256), 0, stream, embed, enorm, ebf);
    hipLaunchKernelGGL(k1_proj,   dim3(1024), dim3(256), 0, stream, z, pw, pb, zp, zbf);
    hipLaunchKernelGGL(k0z_znorm, dim3(1024), dim3(256), 0, stream, zp, znorm);
    hipLaunchKernelGGL(k2_argmin, dim3(512),  dim3(256), 0, stream,
                       zbf, ebf, zp, embed, enorm, znorm, bestk, out1);
    hipLaunchKernelGGL(k3_gather, dim3(1024), dim3(256), 0, stream, embed, bestk, out0);
}